// Round 6
// baseline (339.081 us; speedup 1.0000x reference)
//
#include <hip/hip_runtime.h>

typedef __bf16 bf16;
typedef __attribute__((ext_vector_type(8))) __bf16 bf16x8;
typedef __attribute__((ext_vector_type(4))) __bf16 bf16x4;
typedef __attribute__((ext_vector_type(4))) float f32x4;

#define B_    64
#define N_    197
#define C_    768
#define H_    12
#define HD_   64
#define SCALE_ 0.125f
#define NM_   (N_*N_)         // 38809
#define M_    (B_*N_)         // 12608
#define NEGI_ (-30000.0f)
#define VTP_  200             // vbufT / rpbT row pad

#define GLL16(gptr, lptr) \
  __builtin_amdgcn_global_load_lds((const __attribute__((address_space(1))) unsigned int*)(gptr), \
                                   (__attribute__((address_space(3))) unsigned int*)(lptr), 16, 0, 0)

// ---------------- fused prep: cast x/proj_w, W_eff + bias, rpbT ----------------
// blocks [0,5016): cast; [5016,11928): weff; [11928,13748): rpbT
__global__ __launch_bounds__(256) void prep_kernel(
    const float* __restrict__ x, const float* __restrict__ pw,
    const float* __restrict__ qkv_w, const float* __restrict__ q_bias, const float* __restrict__ v_bias,
    const float* __restrict__ qa, const float* __restrict__ qb,
    const float* __restrict__ ka, const float* __restrict__ kb,
    const float* __restrict__ va, const float* __restrict__ vb,
    const float* __restrict__ table, const int* __restrict__ rpi,
    bf16* __restrict__ xbf, bf16* __restrict__ pwbf,
    bf16* __restrict__ weff, float* __restrict__ biasf, bf16* __restrict__ rpbT)
{
  const int bid = blockIdx.x, tid = threadIdx.x;
  if (bid < 5016) {
    const size_t n1 = (size_t)M_ * C_;   // 9,682,944
    size_t i8 = ((size_t)bid * 256 + tid) * 8;
    const float* src; bf16* dst; size_t off;
    if (i8 < n1) { src = x;  dst = xbf;  off = i8; }
    else         { src = pw; dst = pwbf; off = i8 - n1; }
    float4 f0 = *(const float4*)(src + off);
    float4 f1 = *(const float4*)(src + off + 4);
    bf16x8 v8;
    v8[0] = (bf16)f0.x; v8[1] = (bf16)f0.y; v8[2] = (bf16)f0.z; v8[3] = (bf16)f0.w;
    v8[4] = (bf16)f1.x; v8[5] = (bf16)f1.y; v8[6] = (bf16)f1.z; v8[7] = (bf16)f1.w;
    *(bf16x8*)(dst + off) = v8;
  } else if (bid < 11928) {
    int idx = (bid - 5016) * 256 + tid;          // < 1,769,472 exact
    int d = idx / C_, c = idx - d * C_;
    int sel = d / C_, dd = d - sel * C_;
    const float* a  = (sel == 0) ? qa : (sel == 1) ? ka : va;
    const float* bw = (sel == 0) ? qb : (sel == 1) ? kb : vb;
    float acc = qkv_w[idx];
#pragma unroll
    for (int r = 0; r < 24; ++r)
      acc += bw[dd * 24 + r] * a[r * C_ + c];
    weff[idx] = (bf16)acc;
    if (c == 0)
      biasf[d] = (sel == 0) ? q_bias[dd] : (sel == 2) ? v_bias[dd] : 0.0f;
  } else {
    int idx = (bid - 11928) * 256 + tid;
    if (idx < H_ * NM_) {
      int h = idx / NM_, nm = idx - h * NM_;
      int n = nm / N_, m = nm - n * N_;
      rpbT[((size_t)h * N_ + m) * VTP_ + n] = (bf16)table[rpi[nm] * H_ + h];
    }
  }
}

// ---------------- gemm_bt: C[M,Nn] = A[M,K] @ B[Nn,K]^T, bf16 operands ----------------
// 1-D grid with XCD-chunk remap: v = (bid&7)*CHUNK + (bid>>3); each XCD owns a contiguous
// tile-range (ntile fastest) so its A M-tile slice (~2.4 MB) pins in its private L2.
// MODE 0: scatter q(×SCALE)/k -> [B,H,N,HD]; v -> TRANSPOSED [B,H,HD,VTP_]
// MODE 1: C[m,d] = acc + biasp[d] -> f32 out
template<int MODE, int NT, int CHUNK, int LIM>
__global__ __launch_bounds__(256) void gemm_bt(
    const bf16* __restrict__ A, const bf16* __restrict__ Bw,
    const float* __restrict__ biasp,
    float* __restrict__ Coutf, int M, int Nn, int K,
    bf16* __restrict__ qo, bf16* __restrict__ ko, bf16* __restrict__ vo)
{
  const int vid = (blockIdx.x & 7) * CHUNK + (blockIdx.x >> 3);
  if (vid >= LIM) return;
  const int mt = vid / NT, nt = vid - mt * NT;
  const int rowA0 = mt * 128;   // M-tile
  const int rowB0 = nt * 128;   // N-tile

  __shared__ __align__(16) bf16 As[128 * 64];
  __shared__ __align__(16) bf16 Bs[128 * 64];
  const int tid = threadIdx.x;
  const int lane = tid & 63, w = tid >> 6;
  const int l15 = lane & 15, quad = lane >> 4;
  const int wm = (w & 1) * 64, wn = (w >> 1) * 64;

  f32x4 acc[4][4] = {};

  for (int kt = 0; kt < K; kt += 64) {
#pragma unroll
    for (int i = 0; i < 4; ++i) {
      int lin = (w * 4 + i) * 64 + lane;       // 0..1023
      int r  = lin >> 3;                       // 0..127
      int cb = lin & 7;                        // LDS column block
      int csw = ((cb ^ (r & 7)) << 3);         // swizzled global column (elems)
      int ga = rowA0 + r; if (ga > M - 1) ga = M - 1;
      GLL16(A + (size_t)ga * K + kt + csw, &As[lin * 8]);
      int gb = rowB0 + r; if (gb > Nn - 1) gb = Nn - 1;
      GLL16(Bw + (size_t)gb * K + kt + csw, &Bs[lin * 8]);
    }
    __syncthreads();
#pragma unroll
    for (int ks = 0; ks < 2; ++ks) {
      const int cb = ks * 4 + quad;            // k-block 0..7
      const int sw = (cb ^ (l15 & 7)) << 3;
      bf16x8 af[4], bfr[4];
#pragma unroll
      for (int i = 0; i < 4; ++i)
        af[i] = *(const bf16x8*)(&As[(wm + i * 16 + l15) * 64 + sw]);
#pragma unroll
      for (int j = 0; j < 4; ++j)
        bfr[j] = *(const bf16x8*)(&Bs[(wn + j * 16 + l15) * 64 + sw]);
#pragma unroll
      for (int i = 0; i < 4; ++i)
#pragma unroll
        for (int j = 0; j < 4; ++j)
          acc[i][j] = __builtin_amdgcn_mfma_f32_16x16x32_bf16(af[i], bfr[j], acc[i][j], 0, 0, 0);
    }
    __syncthreads();
  }

#pragma unroll
  for (int i = 0; i < 4; ++i) {
#pragma unroll
    for (int j = 0; j < 4; ++j) {
#pragma unroll
      for (int r = 0; r < 4; ++r) {
        int m = rowA0 + wm + i * 16 + quad * 4 + r;
        int d = rowB0 + wn + j * 16 + l15;
        if (m >= M) continue;
        float v = acc[i][j][r] + biasp[d];
        if (MODE == 0) {
          int b = m / N_, n = m - b * N_;
          int sel = d / C_, dd = d - sel * C_;
          int h = dd >> 6, hd = dd & 63;
          if (sel == 0)
            qo[(((size_t)b * H_ + h) * N_ + n) * HD_ + hd] = (bf16)(v * SCALE_);
          else if (sel == 1)
            ko[(((size_t)b * H_ + h) * N_ + n) * HD_ + hd] = (bf16)v;
          else
            vo[(((size_t)b * H_ + h) * HD_ + hd) * VTP_ + n] = (bf16)v;   // transposed
        } else {
          Coutf[(size_t)m * Nn + d] = v;
        }
      }
    }
  }
}

// ---------------- attention: per (qtile, h, b) block, barrier-free, max-free softmax ----------------
#define SW 232   // P row stride (bf16 elems); PV consumes cols 0..223
__global__ __launch_bounds__(256) void attn_kernel(
    const bf16* __restrict__ q, const bf16* __restrict__ k, const bf16* __restrict__ vT_g,
    const bf16* __restrict__ rpbT, bf16* __restrict__ out)
{
  __shared__ __align__(16) bf16 s_lds[64 * SW];   // P tile (each wave owns its 16 rows)

  const int tid = threadIdx.x;
  const int lane = tid & 63, w = tid >> 6;
  const int l15 = lane & 15, quad = lane >> 4;
  const int qt = blockIdx.x, h = blockIdx.y, b = blockIdx.z;
  const size_t bh = ((size_t)b * H_ + h) * N_ * HD_;
  const bf16* qb = q + bh;
  const bf16* kb = k + bh;
  const bf16* vg = vT_g + ((size_t)b * H_ + h) * HD_ * VTP_;

  // zero this wave's P pad cols [208,224)  (QK pass writes cols 0..207)
  if (quad < 2)
    *(uint4*)(&s_lds[(w * 16 + l15) * SW + 208 + quad * 8]) = (uint4){0, 0, 0, 0};

  // ---- fused pass: S = Q K^T + rpb, P = exp(S), rowsum ----
  const int row0 = qt * 64 + w * 16;
  int qm = row0 + l15; if (qm > N_ - 1) qm = N_ - 1;
  bf16x8 aq0 = *(const bf16x8*)(qb + qm * HD_ + quad * 8);
  bf16x8 aq1 = *(const bf16x8*)(qb + qm * HD_ + 32 + quad * 8);

  int rbase = row0 + quad * 4; if (rbase > N_ - 1) rbase = N_ - 1;  // stays 4-aligned except clamp (aligned too)

  float sum[4] = {0.f, 0.f, 0.f, 0.f};
#pragma unroll
  for (int jt = 0; jt < 13; ++jt) {
    int col = jt * 16 + l15;
    int kn = col; if (kn > N_ - 1) kn = N_ - 1;
    bf16x8 bk0 = *(const bf16x8*)(kb + kn * HD_ + quad * 8);
    bf16x8 bk1 = *(const bf16x8*)(kb + kn * HD_ + 32 + quad * 8);
    bf16x4 rb = *(const bf16x4*)(rpbT + ((size_t)h * N_ + kn) * VTP_ + rbase);
    f32x4 s = {0.f, 0.f, 0.f, 0.f};
    s = __builtin_amdgcn_mfma_f32_16x16x32_bf16(aq0, bk0, s, 0, 0, 0);
    s = __builtin_amdgcn_mfma_f32_16x16x32_bf16(aq1, bk1, s, 0, 0, 0);
#pragma unroll
    for (int r = 0; r < 4; ++r) {
      int row = row0 + quad * 4 + r;
      // scores are O(10); pads get -30000 -> exp underflows to exactly 0
      float sv = (col < N_ && row < N_) ? (s[r] + (float)rb[r]) : NEGI_;
      float p = __expf(sv);
      bf16 pb = (bf16)p;
      s_lds[(w * 16 + quad * 4 + r) * SW + col] = pb;
      sum[r] += (float)pb;
    }
  }
#pragma unroll
  for (int r = 0; r < 4; ++r) {
    sum[r] += __shfl_xor(sum[r], 1);
    sum[r] += __shfl_xor(sum[r], 2);
    sum[r] += __shfl_xor(sum[r], 4);
    sum[r] += __shfl_xor(sum[r], 8);
  }
  float inv[4];
#pragma unroll
  for (int r = 0; r < 4; ++r) inv[r] = 1.0f / fmaxf(sum[r], 1e-20f);

  // ---- phase B: O = P @ V  (V^T fragments straight from global; pads hit exact-zero P) ----
  f32x4 o[4] = {};
#pragma unroll
  for (int kk = 0; kk < 7; ++kk) {
    bf16x8 ap = *(const bf16x8*)(&s_lds[(w * 16 + l15) * SW + kk * 32 + quad * 8]);
#pragma unroll
    for (int j2 = 0; j2 < 4; ++j2) {
      bf16x8 bv = *(const bf16x8*)(vg + (j2 * 16 + l15) * VTP_ + kk * 32 + quad * 8);
      o[j2] = __builtin_amdgcn_mfma_f32_16x16x32_bf16(ap, bv, o[j2], 0, 0, 0);
    }
  }
#pragma unroll
  for (int j2 = 0; j2 < 4; ++j2) {
#pragma unroll
    for (int r = 0; r < 4; ++r) {
      int row = qt * 64 + w * 16 + quad * 4 + r;
      int hd = j2 * 16 + l15;
      if (row < N_)
        out[((size_t)b * N_ + row) * C_ + h * HD_ + hd] = (bf16)(o[j2][r] * inv[r]);
    }
  }
}

// ---------------- launch ----------------
extern "C" void kernel_launch(void* const* d_in, const int* in_sizes, int n_in,
                              void* d_out, int out_size, void* d_ws, size_t ws_size,
                              hipStream_t stream)
{
  const float* x      = (const float*)d_in[0];
  const float* qkv_w  = (const float*)d_in[1];
  const float* q_bias = (const float*)d_in[2];
  const float* v_bias = (const float*)d_in[3];
  const float* q_la   = (const float*)d_in[4];
  const float* q_lb   = (const float*)d_in[5];
  const float* k_la   = (const float*)d_in[6];
  const float* k_lb   = (const float*)d_in[7];
  const float* v_la   = (const float*)d_in[8];
  const float* v_lb   = (const float*)d_in[9];
  const float* rpt    = (const float*)d_in[10];
  const float* proj_w = (const float*)d_in[11];
  const float* proj_b = (const float*)d_in[12];
  const int*   rpi    = (const int*)d_in[13];
  float* out = (float*)d_out;

  char* ws = (char*)d_ws;
  // layout (16B-aligned); xbf dead after gemm<0>, reused as aout
  bf16*  xbf   = (bf16*)(ws);                         // 19,365,888 B
  bf16*  aout  = (bf16*)(ws);                         // alias
  bf16*  weff  = (bf16*)(ws + 19365888);              //  3,538,944 B
  float* biasf = (float*)(ws + 22904832);             //      9,216 B
  bf16*  pwbf  = (bf16*)(ws + 22914048);              //  1,179,648 B
  bf16*  qbuf  = (bf16*)(ws + 24093696);              // 19,365,888 B
  bf16*  kbuf  = (bf16*)(ws + 43459584);              // 19,365,888 B
  bf16*  vbufT = (bf16*)(ws + 62825472);              // 19,660,800 (+128 slack)
  bf16*  rpbT  = (bf16*)(ws + 82486400);              // 945,600
  // total ws use ≈ 83.4 MB

  prep_kernel<<<13748, 256, 0, stream>>>(
      x, proj_w, qkv_w, q_bias, v_bias, q_la, q_lb, k_la, k_lb, v_la, v_lb,
      rpt, rpi, xbf, pwbf, weff, biasf, rpbT);

  // 99 M-tiles x 18 N-tiles = 1782 blocks, pad to 1784 (mult of 8); CHUNK = 223
  gemm_bt<0, 18, 223, 1782><<<1784, 256, 0, stream>>>(
      xbf, weff, biasf, nullptr, M_, 3 * C_, C_, qbuf, kbuf, vbufT);

  attn_kernel<<<dim3(4, H_, B_), 256, 0, stream>>>(qbuf, kbuf, vbufT, rpbT, aout);

  // 99 x 6 = 594 blocks, pad to 600; CHUNK = 75
  gemm_bt<1, 6, 75, 594><<<600, 256, 0, stream>>>(
      aout, pwbf, proj_b, out, M_, C_, C_, nullptr, nullptr, nullptr);
}

// Round 7
// 325.790 us; speedup vs baseline: 1.0408x; 1.0408x over previous
//
#include <hip/hip_runtime.h>

typedef __bf16 bf16;
typedef __attribute__((ext_vector_type(8))) __bf16 bf16x8;
typedef __attribute__((ext_vector_type(4))) __bf16 bf16x4;
typedef __attribute__((ext_vector_type(4))) float f32x4;

#define B_    64
#define N_    197
#define C_    768
#define H_    12
#define HD_   64
#define SCALE_ 0.125f
#define NM_   (N_*N_)         // 38809
#define M_    (B_*N_)         // 12608
#define NEGI_ (-30000.0f)
#define VTP_  200             // vbufT / rpbT row pad

#define GLL16(gptr, lptr) \
  __builtin_amdgcn_global_load_lds((const __attribute__((address_space(1))) unsigned int*)(gptr), \
                                   (__attribute__((address_space(3))) unsigned int*)(lptr), 16, 0, 0)

// ---------------- fused prep: cast x/proj_w, W_eff + bias, rpbT ----------------
// blocks [0,5016): cast; [5016,11928): weff; [11928,13748): rpbT
__global__ __launch_bounds__(256) void prep_kernel(
    const float* __restrict__ x, const float* __restrict__ pw,
    const float* __restrict__ qkv_w, const float* __restrict__ q_bias, const float* __restrict__ v_bias,
    const float* __restrict__ qa, const float* __restrict__ qb,
    const float* __restrict__ ka, const float* __restrict__ kb,
    const float* __restrict__ va, const float* __restrict__ vb,
    const float* __restrict__ table, const int* __restrict__ rpi,
    bf16* __restrict__ xbf, bf16* __restrict__ pwbf,
    bf16* __restrict__ weff, float* __restrict__ biasf, bf16* __restrict__ rpbT)
{
  const int bid = blockIdx.x, tid = threadIdx.x;
  if (bid < 5016) {
    const size_t n1 = (size_t)M_ * C_;   // 9,682,944
    size_t i8 = ((size_t)bid * 256 + tid) * 8;
    const float* src; bf16* dst; size_t off;
    if (i8 < n1) { src = x;  dst = xbf;  off = i8; }
    else         { src = pw; dst = pwbf; off = i8 - n1; }
    float4 f0 = *(const float4*)(src + off);
    float4 f1 = *(const float4*)(src + off + 4);
    bf16x8 v8;
    v8[0] = (bf16)f0.x; v8[1] = (bf16)f0.y; v8[2] = (bf16)f0.z; v8[3] = (bf16)f0.w;
    v8[4] = (bf16)f1.x; v8[5] = (bf16)f1.y; v8[6] = (bf16)f1.z; v8[7] = (bf16)f1.w;
    *(bf16x8*)(dst + off) = v8;
  } else if (bid < 11928) {
    int idx = (bid - 5016) * 256 + tid;          // < 1,769,472 exact
    int d = idx / C_, c = idx - d * C_;
    int sel = d / C_, dd = d - sel * C_;
    const float* a  = (sel == 0) ? qa : (sel == 1) ? ka : va;
    const float* bw = (sel == 0) ? qb : (sel == 1) ? kb : vb;
    float acc = qkv_w[idx];
#pragma unroll
    for (int r = 0; r < 24; ++r)
      acc += bw[dd * 24 + r] * a[r * C_ + c];
    weff[idx] = (bf16)acc;
    if (c == 0)
      biasf[d] = (sel == 0) ? q_bias[dd] : (sel == 2) ? v_bias[dd] : 0.0f;
  } else {
    int idx = (bid - 11928) * 256 + tid;
    if (idx < H_ * NM_) {
      int h = idx / NM_, nm = idx - h * NM_;
      int n = nm / N_, m = nm - n * N_;
      rpbT[((size_t)h * N_ + m) * VTP_ + n] = (bf16)table[rpi[nm] * H_ + h];
    }
  }
}

// ---------------- gemm_bt: C[M,Nn] = A[M,K] @ B[Nn,K]^T, bf16 operands ----------------
// grid: (Nn/128, ceil(M/128)) 2D, N-tile fastest — concurrent blocks share one A-tile
// (L3-served) and sweep B together. XCD-chunk remap tried in R6: FETCH -28% but dur +21%
// (kernel is latency-bound, not BW-bound) — reverted.
// MODE 0: scatter q(×SCALE)/k -> [B,H,N,HD]; v -> TRANSPOSED [B,H,HD,VTP_]
// MODE 1: C[m,d] = acc + biasp[d] -> f32 out
template<int MODE>
__global__ __launch_bounds__(256) void gemm_bt(
    const bf16* __restrict__ A, const bf16* __restrict__ Bw,
    const float* __restrict__ biasp,
    float* __restrict__ Coutf, int M, int Nn, int K,
    bf16* __restrict__ qo, bf16* __restrict__ ko, bf16* __restrict__ vo)
{
  __shared__ __align__(16) bf16 As[128 * 64];
  __shared__ __align__(16) bf16 Bs[128 * 64];
  const int tid = threadIdx.x;
  const int lane = tid & 63, w = tid >> 6;
  const int l15 = lane & 15, quad = lane >> 4;
  const int wm = (w & 1) * 64, wn = (w >> 1) * 64;
  const int rowA0 = blockIdx.y * 128;   // M-tile
  const int rowB0 = blockIdx.x * 128;   // N-tile (fastest-varying)

  f32x4 acc[4][4] = {};

  for (int kt = 0; kt < K; kt += 64) {
#pragma unroll
    for (int i = 0; i < 4; ++i) {
      int lin = (w * 4 + i) * 64 + lane;       // 0..1023
      int r  = lin >> 3;                       // 0..127
      int cb = lin & 7;                        // LDS column block
      int csw = ((cb ^ (r & 7)) << 3);         // swizzled global column (elems)
      int ga = rowA0 + r; if (ga > M - 1) ga = M - 1;
      GLL16(A + (size_t)ga * K + kt + csw, &As[lin * 8]);
      int gb = rowB0 + r; if (gb > Nn - 1) gb = Nn - 1;
      GLL16(Bw + (size_t)gb * K + kt + csw, &Bs[lin * 8]);
    }
    __syncthreads();
#pragma unroll
    for (int ks = 0; ks < 2; ++ks) {
      const int cb = ks * 4 + quad;            // k-block 0..7
      const int sw = (cb ^ (l15 & 7)) << 3;
      bf16x8 af[4], bfr[4];
#pragma unroll
      for (int i = 0; i < 4; ++i)
        af[i] = *(const bf16x8*)(&As[(wm + i * 16 + l15) * 64 + sw]);
#pragma unroll
      for (int j = 0; j < 4; ++j)
        bfr[j] = *(const bf16x8*)(&Bs[(wn + j * 16 + l15) * 64 + sw]);
#pragma unroll
      for (int i = 0; i < 4; ++i)
#pragma unroll
        for (int j = 0; j < 4; ++j)
          acc[i][j] = __builtin_amdgcn_mfma_f32_16x16x32_bf16(af[i], bfr[j], acc[i][j], 0, 0, 0);
    }
    __syncthreads();
  }

#pragma unroll
  for (int i = 0; i < 4; ++i) {
#pragma unroll
    for (int j = 0; j < 4; ++j) {
#pragma unroll
      for (int r = 0; r < 4; ++r) {
        int m = rowA0 + wm + i * 16 + quad * 4 + r;
        int d = rowB0 + wn + j * 16 + l15;
        if (m >= M) continue;
        float v = acc[i][j][r] + biasp[d];
        if (MODE == 0) {
          int b = m / N_, n = m - b * N_;
          int sel = d / C_, dd = d - sel * C_;
          int h = dd >> 6, hd = dd & 63;
          if (sel == 0)
            qo[(((size_t)b * H_ + h) * N_ + n) * HD_ + hd] = (bf16)(v * SCALE_);
          else if (sel == 1)
            ko[(((size_t)b * H_ + h) * N_ + n) * HD_ + hd] = (bf16)v;
          else
            vo[(((size_t)b * H_ + h) * HD_ + hd) * VTP_ + n] = (bf16)v;   // transposed
        } else {
          Coutf[(size_t)m * Nn + d] = v;
        }
      }
    }
  }
}

// ---------------- attention: per (qtile, h, b) block, barrier-free, max-free softmax ----------------
#define SW 232   // P row stride (bf16 elems); PV consumes cols 0..223
__global__ __launch_bounds__(256) void attn_kernel(
    const bf16* __restrict__ q, const bf16* __restrict__ k, const bf16* __restrict__ vT_g,
    const bf16* __restrict__ rpbT, bf16* __restrict__ out)
{
  __shared__ __align__(16) bf16 s_lds[64 * SW];   // P tile (each wave owns its 16 rows)

  const int tid = threadIdx.x;
  const int lane = tid & 63, w = tid >> 6;
  const int l15 = lane & 15, quad = lane >> 4;
  const int qt = blockIdx.x, h = blockIdx.y, b = blockIdx.z;
  const size_t bh = ((size_t)b * H_ + h) * N_ * HD_;
  const bf16* qb = q + bh;
  const bf16* kb = k + bh;
  const bf16* vg = vT_g + ((size_t)b * H_ + h) * HD_ * VTP_;

  // zero this wave's P pad cols [208,224)  (QK pass writes cols 0..207)
  if (quad < 2)
    *(uint4*)(&s_lds[(w * 16 + l15) * SW + 208 + quad * 8]) = (uint4){0, 0, 0, 0};

  // ---- fused pass: S = Q K^T + rpb, P = exp(S), rowsum ----
  const int row0 = qt * 64 + w * 16;
  int qm = row0 + l15; if (qm > N_ - 1) qm = N_ - 1;
  bf16x8 aq0 = *(const bf16x8*)(qb + qm * HD_ + quad * 8);
  bf16x8 aq1 = *(const bf16x8*)(qb + qm * HD_ + 32 + quad * 8);

  int rbase = row0 + quad * 4; if (rbase > N_ - 1) rbase = N_ - 1;

  float sum[4] = {0.f, 0.f, 0.f, 0.f};
#pragma unroll
  for (int jt = 0; jt < 13; ++jt) {
    int col = jt * 16 + l15;
    int kn = col; if (kn > N_ - 1) kn = N_ - 1;
    bf16x8 bk0 = *(const bf16x8*)(kb + kn * HD_ + quad * 8);
    bf16x8 bk1 = *(const bf16x8*)(kb + kn * HD_ + 32 + quad * 8);
    bf16x4 rb = *(const bf16x4*)(rpbT + ((size_t)h * N_ + kn) * VTP_ + rbase);
    f32x4 s = {0.f, 0.f, 0.f, 0.f};
    s = __builtin_amdgcn_mfma_f32_16x16x32_bf16(aq0, bk0, s, 0, 0, 0);
    s = __builtin_amdgcn_mfma_f32_16x16x32_bf16(aq1, bk1, s, 0, 0, 0);
#pragma unroll
    for (int r = 0; r < 4; ++r) {
      int row = row0 + quad * 4 + r;
      // scores are O(10); pads get -30000 -> exp underflows to exactly 0
      float sv = (col < N_ && row < N_) ? (s[r] + (float)rb[r]) : NEGI_;
      float p = __expf(sv);
      bf16 pb = (bf16)p;
      s_lds[(w * 16 + quad * 4 + r) * SW + col] = pb;
      sum[r] += (float)pb;
    }
  }

  // prefetch phase-B kk=0 V fragments into the shuffle-latency shadow
  bf16x8 bv0[4];
#pragma unroll
  for (int j2 = 0; j2 < 4; ++j2)
    bv0[j2] = *(const bf16x8*)(vg + (j2 * 16 + l15) * VTP_ + quad * 8);

#pragma unroll
  for (int r = 0; r < 4; ++r) {
    sum[r] += __shfl_xor(sum[r], 1);
    sum[r] += __shfl_xor(sum[r], 2);
    sum[r] += __shfl_xor(sum[r], 4);
    sum[r] += __shfl_xor(sum[r], 8);
  }
  float inv[4];
#pragma unroll
  for (int r = 0; r < 4; ++r) inv[r] = 1.0f / fmaxf(sum[r], 1e-20f);

  // ---- phase B: O = P @ V  (V^T fragments straight from global; pads hit exact-zero P) ----
  f32x4 o[4] = {};
  {
    bf16x8 ap = *(const bf16x8*)(&s_lds[(w * 16 + l15) * SW + quad * 8]);
#pragma unroll
    for (int j2 = 0; j2 < 4; ++j2)
      o[j2] = __builtin_amdgcn_mfma_f32_16x16x32_bf16(ap, bv0[j2], o[j2], 0, 0, 0);
  }
#pragma unroll
  for (int kk = 1; kk < 7; ++kk) {
    bf16x8 ap = *(const bf16x8*)(&s_lds[(w * 16 + l15) * SW + kk * 32 + quad * 8]);
#pragma unroll
    for (int j2 = 0; j2 < 4; ++j2) {
      bf16x8 bv = *(const bf16x8*)(vg + (j2 * 16 + l15) * VTP_ + kk * 32 + quad * 8);
      o[j2] = __builtin_amdgcn_mfma_f32_16x16x32_bf16(ap, bv, o[j2], 0, 0, 0);
    }
  }
#pragma unroll
  for (int j2 = 0; j2 < 4; ++j2) {
#pragma unroll
    for (int r = 0; r < 4; ++r) {
      int row = qt * 64 + w * 16 + quad * 4 + r;
      int hd = j2 * 16 + l15;
      if (row < N_)
        out[((size_t)b * N_ + row) * C_ + h * HD_ + hd] = (bf16)(o[j2][r] * inv[r]);
    }
  }
}

// ---------------- launch ----------------
extern "C" void kernel_launch(void* const* d_in, const int* in_sizes, int n_in,
                              void* d_out, int out_size, void* d_ws, size_t ws_size,
                              hipStream_t stream)
{
  const float* x      = (const float*)d_in[0];
  const float* qkv_w  = (const float*)d_in[1];
  const float* q_bias = (const float*)d_in[2];
  const float* v_bias = (const float*)d_in[3];
  const float* q_la   = (const float*)d_in[4];
  const float* q_lb   = (const float*)d_in[5];
  const float* k_la   = (const float*)d_in[6];
  const float* k_lb   = (const float*)d_in[7];
  const float* v_la   = (const float*)d_in[8];
  const float* v_lb   = (const float*)d_in[9];
  const float* rpt    = (const float*)d_in[10];
  const float* proj_w = (const float*)d_in[11];
  const float* proj_b = (const float*)d_in[12];
  const int*   rpi    = (const int*)d_in[13];
  float* out = (float*)d_out;

  char* ws = (char*)d_ws;
  // layout (16B-aligned); xbf dead after gemm<0>, reused as aout
  bf16*  xbf   = (bf16*)(ws);                         // 19,365,888 B
  bf16*  aout  = (bf16*)(ws);                         // alias
  bf16*  weff  = (bf16*)(ws + 19365888);              //  3,538,944 B
  float* biasf = (float*)(ws + 22904832);             //      9,216 B
  bf16*  pwbf  = (bf16*)(ws + 22914048);              //  1,179,648 B
  bf16*  qbuf  = (bf16*)(ws + 24093696);              // 19,365,888 B
  bf16*  kbuf  = (bf16*)(ws + 43459584);              // 19,365,888 B
  bf16*  vbufT = (bf16*)(ws + 62825472);              // 19,660,800 (+128 slack)
  bf16*  rpbT  = (bf16*)(ws + 82486400);              // 945,600
  // total ws use ≈ 83.4 MB

  prep_kernel<<<13748, 256, 0, stream>>>(
      x, proj_w, qkv_w, q_bias, v_bias, q_la, q_lb, k_la, k_lb, v_la, v_lb,
      rpt, rpi, xbf, pwbf, weff, biasf, rpbT);

  gemm_bt<0><<<dim3(18, 99), 256, 0, stream>>>(
      xbf, weff, biasf, nullptr, M_, 3 * C_, C_, qbuf, kbuf, vbufT);

  attn_kernel<<<dim3(4, H_, B_), 256, 0, stream>>>(qbuf, kbuf, vbufT, rpbT, aout);

  gemm_bt<1><<<dim3(6, 99), 256, 0, stream>>>(
      aout, pwbf, proj_b, out, M_, C_, C_, nullptr, nullptr, nullptr);
}

// Round 8
// 312.463 us; speedup vs baseline: 1.0852x; 1.0427x over previous
//
#include <hip/hip_runtime.h>

typedef __bf16 bf16;
typedef __attribute__((ext_vector_type(8))) __bf16 bf16x8;
typedef __attribute__((ext_vector_type(4))) __bf16 bf16x4;
typedef __attribute__((ext_vector_type(4))) float f32x4;

#define B_    64
#define N_    197
#define C_    768
#define H_    12
#define HD_   64
#define SCALE_ 0.125f
#define NM_   (N_*N_)         // 38809
#define M_    (B_*N_)         // 12608
#define NEGI_ (-30000.0f)
#define VTP_  200             // vbufT / rpbT row pad

#define GLL16(gptr, lptr) \
  __builtin_amdgcn_global_load_lds((const __attribute__((address_space(1))) unsigned int*)(gptr), \
                                   (__attribute__((address_space(3))) unsigned int*)(lptr), 16, 0, 0)

// ---------------- fused prep: cast x/proj_w, W_eff + bias, rpbT ----------------
// blocks [0,5016): cast; [5016,11928): weff; [11928,13748): rpbT
__global__ __launch_bounds__(256) void prep_kernel(
    const float* __restrict__ x, const float* __restrict__ pw,
    const float* __restrict__ qkv_w, const float* __restrict__ q_bias, const float* __restrict__ v_bias,
    const float* __restrict__ qa, const float* __restrict__ qb,
    const float* __restrict__ ka, const float* __restrict__ kb,
    const float* __restrict__ va, const float* __restrict__ vb,
    const float* __restrict__ table, const int* __restrict__ rpi,
    bf16* __restrict__ xbf, bf16* __restrict__ pwbf,
    bf16* __restrict__ weff, float* __restrict__ biasf, bf16* __restrict__ rpbT)
{
  const int bid = blockIdx.x, tid = threadIdx.x;
  if (bid < 5016) {
    const size_t n1 = (size_t)M_ * C_;   // 9,682,944
    size_t i8 = ((size_t)bid * 256 + tid) * 8;
    const float* src; bf16* dst; size_t off;
    if (i8 < n1) { src = x;  dst = xbf;  off = i8; }
    else         { src = pw; dst = pwbf; off = i8 - n1; }
    float4 f0 = *(const float4*)(src + off);
    float4 f1 = *(const float4*)(src + off + 4);
    bf16x8 v8;
    v8[0] = (bf16)f0.x; v8[1] = (bf16)f0.y; v8[2] = (bf16)f0.z; v8[3] = (bf16)f0.w;
    v8[4] = (bf16)f1.x; v8[5] = (bf16)f1.y; v8[6] = (bf16)f1.z; v8[7] = (bf16)f1.w;
    *(bf16x8*)(dst + off) = v8;
  } else if (bid < 11928) {
    int idx = (bid - 5016) * 256 + tid;          // < 1,769,472 exact
    int d = idx / C_, c = idx - d * C_;
    int sel = d / C_, dd = d - sel * C_;
    const float* a  = (sel == 0) ? qa : (sel == 1) ? ka : va;
    const float* bw = (sel == 0) ? qb : (sel == 1) ? kb : vb;
    float acc = qkv_w[idx];
#pragma unroll
    for (int r = 0; r < 24; ++r)
      acc += bw[dd * 24 + r] * a[r * C_ + c];
    weff[idx] = (bf16)acc;
    if (c == 0)
      biasf[d] = (sel == 0) ? q_bias[dd] : (sel == 2) ? v_bias[dd] : 0.0f;
  } else {
    int idx = (bid - 11928) * 256 + tid;
    if (idx < H_ * NM_) {
      int h = idx / NM_, nm = idx - h * NM_;
      int n = nm / N_, m = nm - n * N_;
      rpbT[((size_t)h * N_ + m) * VTP_ + n] = (bf16)table[rpi[nm] * H_ + h];
    }
  }
}

// ---------------- gemm_bt: C[M,Nn] = A[M,K] @ B[Nn,K]^T, bf16 operands ----------------
// grid: (Nn/128, ceil(M/128)) 2D, N-tile fastest.
// __launch_bounds__(256,4): force <=128 unified regs/wave (64 VGPR + 64 AGPR acc)
// -> 4 waves/SIMD. R7 counters: latency-bound (all pipes <28%), occupancy was the lever.
// MODE 0: scatter q(×SCALE)/k -> [B,H,N,HD]; v -> TRANSPOSED [B,H,HD,VTP_]
// MODE 1: C[m,d] = acc + biasp[d] -> f32 out
template<int MODE>
__global__ __launch_bounds__(256, 4) void gemm_bt(
    const bf16* __restrict__ A, const bf16* __restrict__ Bw,
    const float* __restrict__ biasp,
    float* __restrict__ Coutf, int M, int Nn, int K,
    bf16* __restrict__ qo, bf16* __restrict__ ko, bf16* __restrict__ vo)
{
  __shared__ __align__(16) bf16 As[128 * 64];
  __shared__ __align__(16) bf16 Bs[128 * 64];
  const int tid = threadIdx.x;
  const int lane = tid & 63, w = tid >> 6;
  const int l15 = lane & 15, quad = lane >> 4;
  const int wm = (w & 1) * 64, wn = (w >> 1) * 64;
  const int rowA0 = blockIdx.y * 128;   // M-tile
  const int rowB0 = blockIdx.x * 128;   // N-tile (fastest-varying)

  f32x4 acc[4][4] = {};

  for (int kt = 0; kt < K; kt += 64) {
#pragma unroll
    for (int i = 0; i < 4; ++i) {
      int lin = (w * 4 + i) * 64 + lane;       // 0..1023
      int r  = lin >> 3;                       // 0..127
      int cb = lin & 7;                        // LDS column block
      int csw = ((cb ^ (r & 7)) << 3);         // swizzled global column (elems)
      int ga = rowA0 + r; if (ga > M - 1) ga = M - 1;
      GLL16(A + (size_t)ga * K + kt + csw, &As[lin * 8]);
      int gb = rowB0 + r; if (gb > Nn - 1) gb = Nn - 1;
      GLL16(Bw + (size_t)gb * K + kt + csw, &Bs[lin * 8]);
    }
    __syncthreads();
#pragma unroll
    for (int ks = 0; ks < 2; ++ks) {
      const int cb = ks * 4 + quad;            // k-block 0..7
      const int sw = (cb ^ (l15 & 7)) << 3;
      bf16x8 af[4], bfr[4];
#pragma unroll
      for (int i = 0; i < 4; ++i)
        af[i] = *(const bf16x8*)(&As[(wm + i * 16 + l15) * 64 + sw]);
#pragma unroll
      for (int j = 0; j < 4; ++j)
        bfr[j] = *(const bf16x8*)(&Bs[(wn + j * 16 + l15) * 64 + sw]);
#pragma unroll
      for (int i = 0; i < 4; ++i)
#pragma unroll
        for (int j = 0; j < 4; ++j)
          acc[i][j] = __builtin_amdgcn_mfma_f32_16x16x32_bf16(af[i], bfr[j], acc[i][j], 0, 0, 0);
    }
    __syncthreads();
  }

#pragma unroll
  for (int i = 0; i < 4; ++i) {
#pragma unroll
    for (int j = 0; j < 4; ++j) {
#pragma unroll
      for (int r = 0; r < 4; ++r) {
        int m = rowA0 + wm + i * 16 + quad * 4 + r;
        int d = rowB0 + wn + j * 16 + l15;
        if (m >= M) continue;
        float v = acc[i][j][r] + biasp[d];
        if (MODE == 0) {
          int b = m / N_, n = m - b * N_;
          int sel = d / C_, dd = d - sel * C_;
          int h = dd >> 6, hd = dd & 63;
          if (sel == 0)
            qo[(((size_t)b * H_ + h) * N_ + n) * HD_ + hd] = (bf16)(v * SCALE_);
          else if (sel == 1)
            ko[(((size_t)b * H_ + h) * N_ + n) * HD_ + hd] = (bf16)v;
          else
            vo[(((size_t)b * H_ + h) * HD_ + hd) * VTP_ + n] = (bf16)v;   // transposed
        } else {
          Coutf[(size_t)m * Nn + d] = v;
        }
      }
    }
  }
}

// ---------------- attention: per (qtile, h, b) block, barrier-free, max-free softmax ----------------
#define SW 232   // P row stride (bf16 elems); PV consumes cols 0..223
__global__ __launch_bounds__(256) void attn_kernel(
    const bf16* __restrict__ q, const bf16* __restrict__ k, const bf16* __restrict__ vT_g,
    const bf16* __restrict__ rpbT, bf16* __restrict__ out)
{
  __shared__ __align__(16) bf16 s_lds[64 * SW];   // P tile (each wave owns its 16 rows)

  const int tid = threadIdx.x;
  const int lane = tid & 63, w = tid >> 6;
  const int l15 = lane & 15, quad = lane >> 4;
  const int qt = blockIdx.x, h = blockIdx.y, b = blockIdx.z;
  const size_t bh = ((size_t)b * H_ + h) * N_ * HD_;
  const bf16* qb = q + bh;
  const bf16* kb = k + bh;
  const bf16* vg = vT_g + ((size_t)b * H_ + h) * HD_ * VTP_;

  // zero this wave's P pad cols [208,224)  (QK pass writes cols 0..207)
  if (quad < 2)
    *(uint4*)(&s_lds[(w * 16 + l15) * SW + 208 + quad * 8]) = (uint4){0, 0, 0, 0};

  // ---- fused pass: S = Q K^T + rpb, P = exp(S), rowsum ----
  const int row0 = qt * 64 + w * 16;
  int qm = row0 + l15; if (qm > N_ - 1) qm = N_ - 1;
  bf16x8 aq0 = *(const bf16x8*)(qb + qm * HD_ + quad * 8);
  bf16x8 aq1 = *(const bf16x8*)(qb + qm * HD_ + 32 + quad * 8);

  int rbase = row0 + quad * 4; if (rbase > N_ - 1) rbase = N_ - 1;

  float sum[4] = {0.f, 0.f, 0.f, 0.f};
#pragma unroll
  for (int jt = 0; jt < 13; ++jt) {
    int col = jt * 16 + l15;
    int kn = col; if (kn > N_ - 1) kn = N_ - 1;
    bf16x8 bk0 = *(const bf16x8*)(kb + kn * HD_ + quad * 8);
    bf16x8 bk1 = *(const bf16x8*)(kb + kn * HD_ + 32 + quad * 8);
    bf16x4 rb = *(const bf16x4*)(rpbT + ((size_t)h * N_ + kn) * VTP_ + rbase);
    f32x4 s = {0.f, 0.f, 0.f, 0.f};
    s = __builtin_amdgcn_mfma_f32_16x16x32_bf16(aq0, bk0, s, 0, 0, 0);
    s = __builtin_amdgcn_mfma_f32_16x16x32_bf16(aq1, bk1, s, 0, 0, 0);
#pragma unroll
    for (int r = 0; r < 4; ++r) {
      int row = row0 + quad * 4 + r;
      // scores are O(10); pads get -30000 -> exp underflows to exactly 0
      float sv = (col < N_ && row < N_) ? (s[r] + (float)rb[r]) : NEGI_;
      float p = __expf(sv);
      bf16 pb = (bf16)p;
      s_lds[(w * 16 + quad * 4 + r) * SW + col] = pb;
      sum[r] += (float)pb;
    }
  }

  // prefetch phase-B kk=0 V fragments into the shuffle-latency shadow
  bf16x8 bv0[4];
#pragma unroll
  for (int j2 = 0; j2 < 4; ++j2)
    bv0[j2] = *(const bf16x8*)(vg + (j2 * 16 + l15) * VTP_ + quad * 8);

#pragma unroll
  for (int r = 0; r < 4; ++r) {
    sum[r] += __shfl_xor(sum[r], 1);
    sum[r] += __shfl_xor(sum[r], 2);
    sum[r] += __shfl_xor(sum[r], 4);
    sum[r] += __shfl_xor(sum[r], 8);
  }
  float inv[4];
#pragma unroll
  for (int r = 0; r < 4; ++r) inv[r] = 1.0f / fmaxf(sum[r], 1e-20f);

  // ---- phase B: O = P @ V  (V^T fragments straight from global; pads hit exact-zero P) ----
  f32x4 o[4] = {};
  {
    bf16x8 ap = *(const bf16x8*)(&s_lds[(w * 16 + l15) * SW + quad * 8]);
#pragma unroll
    for (int j2 = 0; j2 < 4; ++j2)
      o[j2] = __builtin_amdgcn_mfma_f32_16x16x32_bf16(ap, bv0[j2], o[j2], 0, 0, 0);
  }
#pragma unroll
  for (int kk = 1; kk < 7; ++kk) {
    bf16x8 ap = *(const bf16x8*)(&s_lds[(w * 16 + l15) * SW + kk * 32 + quad * 8]);
#pragma unroll
    for (int j2 = 0; j2 < 4; ++j2) {
      bf16x8 bv = *(const bf16x8*)(vg + (j2 * 16 + l15) * VTP_ + kk * 32 + quad * 8);
      o[j2] = __builtin_amdgcn_mfma_f32_16x16x32_bf16(ap, bv, o[j2], 0, 0, 0);
    }
  }
#pragma unroll
  for (int j2 = 0; j2 < 4; ++j2) {
#pragma unroll
    for (int r = 0; r < 4; ++r) {
      int row = qt * 64 + w * 16 + quad * 4 + r;
      int hd = j2 * 16 + l15;
      if (row < N_)
        out[((size_t)b * N_ + row) * C_ + h * HD_ + hd] = (bf16)(o[j2][r] * inv[r]);
    }
  }
}

// ---------------- launch ----------------
extern "C" void kernel_launch(void* const* d_in, const int* in_sizes, int n_in,
                              void* d_out, int out_size, void* d_ws, size_t ws_size,
                              hipStream_t stream)
{
  const float* x      = (const float*)d_in[0];
  const float* qkv_w  = (const float*)d_in[1];
  const float* q_bias = (const float*)d_in[2];
  const float* v_bias = (const float*)d_in[3];
  const float* q_la   = (const float*)d_in[4];
  const float* q_lb   = (const float*)d_in[5];
  const float* k_la   = (const float*)d_in[6];
  const float* k_lb   = (const float*)d_in[7];
  const float* v_la   = (const float*)d_in[8];
  const float* v_lb   = (const float*)d_in[9];
  const float* rpt    = (const float*)d_in[10];
  const float* proj_w = (const float*)d_in[11];
  const float* proj_b = (const float*)d_in[12];
  const int*   rpi    = (const int*)d_in[13];
  float* out = (float*)d_out;

  char* ws = (char*)d_ws;
  // layout (16B-aligned); xbf dead after gemm<0>, reused as aout
  bf16*  xbf   = (bf16*)(ws);                         // 19,365,888 B
  bf16*  aout  = (bf16*)(ws);                         // alias
  bf16*  weff  = (bf16*)(ws + 19365888);              //  3,538,944 B
  float* biasf = (float*)(ws + 22904832);             //      9,216 B
  bf16*  pwbf  = (bf16*)(ws + 22914048);              //  1,179,648 B
  bf16*  qbuf  = (bf16*)(ws + 24093696);              // 19,365,888 B
  bf16*  kbuf  = (bf16*)(ws + 43459584);              // 19,365,888 B
  bf16*  vbufT = (bf16*)(ws + 62825472);              // 19,660,800 (+128 slack)
  bf16*  rpbT  = (bf16*)(ws + 82486400);              // 945,600
  // total ws use ≈ 83.4 MB

  prep_kernel<<<13748, 256, 0, stream>>>(
      x, proj_w, qkv_w, q_bias, v_bias, q_la, q_lb, k_la, k_lb, v_la, v_lb,
      rpt, rpi, xbf, pwbf, weff, biasf, rpbT);

  gemm_bt<0><<<dim3(18, 99), 256, 0, stream>>>(
      xbf, weff, biasf, nullptr, M_, 3 * C_, C_, qbuf, kbuf, vbufT);

  attn_kernel<<<dim3(4, H_, B_), 256, 0, stream>>>(qbuf, kbuf, vbufT, rpbT, aout);

  gemm_bt<1><<<dim3(6, 99), 256, 0, stream>>>(
      aout, pwbf, proj_b, out, M_, C_, C_, nullptr, nullptr, nullptr);
}